// Round 5
// baseline (2126.858 us; speedup 1.0000x reference)
//
#include <hip/hip_runtime.h>

#define BB 128
#define TT 1496
#define CC 768
#define BLOCKS_PER_ROW 374   // TT/4 rows per block (1 row per wave, 4 waves)

// Fused kernel: phase 1 streams hidden_states and writes p[b,t] = h.W (or 0
// for invalid frames). Then the LAST block to finish batch-row b (device-scope
// atomic counter, CUB-style last-block-done) runs the run-mean finalize for
// that row inline — overlapping finalize with the streaming of later rows and
// removing the second launch + grid-drain bubble.
__global__ __launch_bounds__(256) void fused_kernel(
    const float* __restrict__ h,      // (B,T,C)
    const float* __restrict__ W,      // (C)
    const int* __restrict__ lens,     // (B)
    const float* __restrict__ bias,   // (1)
    const int* __restrict__ ids,      // (B,T)
    float* __restrict__ p,            // (B,T) ws
    int* __restrict__ done,           // (B)   ws, zeroed by memset each call
    float* __restrict__ out)          // (B)
{
    __shared__ int   s_last;
    __shared__ float s_acc[4];
    __shared__ float s_cnt[4];

    const int lane = threadIdx.x & 63;
    const int wv   = threadIdx.x >> 6;            // 0..3
    const int b    = blockIdx.y;
    const int t    = blockIdx.x * 4 + wv;         // < 1496 by grid

    int L = lens[b];
    if (L < 1) L = 1;
    if (L > TT) L = TT;

    // ---- phase 1: p[b,t] = dot(h[b,t,:], W) for valid frames ----
    if (t < L) {                                   // wave-uniform
        const float4* r  = reinterpret_cast<const float4*>(h + ((size_t)b * TT + t) * CC);
        const float4* w4 = reinterpret_cast<const float4*>(W);
        float4 a0 = r[lane];
        float4 a1 = r[lane + 64];
        float4 a2 = r[lane + 128];
        float4 w0 = w4[lane];
        float4 w1 = w4[lane + 64];
        float4 w2 = w4[lane + 128];
        float s = a0.x * w0.x + a0.y * w0.y + a0.z * w0.z + a0.w * w0.w
                + a1.x * w1.x + a1.y * w1.y + a1.z * w1.z + a1.w * w1.w
                + a2.x * w2.x + a2.y * w2.y + a2.z * w2.z + a2.w * w2.w;
        #pragma unroll
        for (int off = 32; off > 0; off >>= 1)
            s += __shfl_down(s, off, 64);
        if (lane == 0) p[b * TT + t] = s;
    } else {
        if (lane == 0) p[b * TT + t] = 0.0f;       // deterministic ws, no poison
    }

    // ---- last-block-done handshake (release: fence before atomic) ----
    __syncthreads();                               // drains block's vmem stores
    if (threadIdx.x == 0) {
        __threadfence();                           // device-scope release
        int old = atomicAdd(&done[b], 1);
        s_last = (old == BLOCKS_PER_ROW - 1) ? 1 : 0;
        if (s_last) __threadfence();               // device-scope acquire
    }
    __syncthreads();
    if (!s_last) return;

    // ---- phase 2: finalize row b (only the last block for this b) ----
    const float* pr = p + b * TT;
    const int*   ir = ids + b * TT;

    float acc = 0.0f;   // sum of run means
    float cnt = 0.0f;   // number of runs

    for (int tt = (int)threadIdx.x; tt < L; tt += 256) {
        int  id    = ir[tt];
        bool start = (tt == 0) || (ir[tt - 1] != id);
        if (start) {
            float rs = pr[tt];
            float rl = 1.0f;
            int   j  = tt + 1;
            while (j < L && ir[j] == id) {
                rs += pr[j];
                rl += 1.0f;
                ++j;
            }
            acc += rs / rl;
            cnt += 1.0f;
        }
    }

    #pragma unroll
    for (int off = 32; off > 0; off >>= 1) {
        acc += __shfl_down(acc, off, 64);
        cnt += __shfl_down(cnt, off, 64);
    }
    if (lane == 0) { s_acc[wv] = acc; s_cnt[wv] = cnt; }
    __syncthreads();

    if (threadIdx.x == 0) {
        float a = s_acc[0] + s_acc[1] + s_acc[2] + s_acc[3];
        float c = s_cnt[0] + s_cnt[1] + s_cnt[2] + s_cnt[3];
        out[b] = a / c + bias[0];
    }
}

// ---- fallback pair (proven round-3 path) used only if ws too small ----
__global__ __launch_bounds__(256) void row_dot_kernel(
    const float* __restrict__ h, const float* __restrict__ W,
    const int* __restrict__ lens, float* __restrict__ p)
{
    const int lane = threadIdx.x & 63;
    const int wv   = threadIdx.x >> 6;
    const int t    = blockIdx.x * 4 + wv;
    const int b    = blockIdx.y;
    if (t >= TT) return;
    if (t >= lens[b]) { if (lane == 0) p[b * TT + t] = 0.0f; return; }
    const float4* r  = reinterpret_cast<const float4*>(h + ((size_t)b * TT + t) * CC);
    const float4* w4 = reinterpret_cast<const float4*>(W);
    float4 a0 = r[lane], a1 = r[lane + 64], a2 = r[lane + 128];
    float4 w0 = w4[lane], w1 = w4[lane + 64], w2 = w4[lane + 128];
    float s = a0.x * w0.x + a0.y * w0.y + a0.z * w0.z + a0.w * w0.w
            + a1.x * w1.x + a1.y * w1.y + a1.z * w1.z + a1.w * w1.w
            + a2.x * w2.x + a2.y * w2.y + a2.z * w2.z + a2.w * w2.w;
    #pragma unroll
    for (int off = 32; off > 0; off >>= 1) s += __shfl_down(s, off, 64);
    if (lane == 0) p[b * TT + t] = s;
}

__global__ __launch_bounds__(256) void finalize_kernel(
    const float* __restrict__ p, const int* __restrict__ ids,
    const int* __restrict__ lens, const float* __restrict__ bias,
    float* __restrict__ out)
{
    __shared__ float s_acc[4];
    __shared__ float s_cnt[4];
    const int b = blockIdx.x;
    int L = lens[b];
    if (L < 1) L = 1;
    if (L > TT) L = TT;
    const float* pr = p + b * TT;
    const int*   ir = ids + b * TT;
    float acc = 0.0f, cnt = 0.0f;
    for (int t = (int)threadIdx.x; t < L; t += 256) {
        int  id    = ir[t];
        bool start = (t == 0) || (ir[t - 1] != id);
        if (start) {
            float rs = pr[t]; float rl = 1.0f; int j = t + 1;
            while (j < L && ir[j] == id) { rs += pr[j]; rl += 1.0f; ++j; }
            acc += rs / rl; cnt += 1.0f;
        }
    }
    #pragma unroll
    for (int off = 32; off > 0; off >>= 1) {
        acc += __shfl_down(acc, off, 64);
        cnt += __shfl_down(cnt, off, 64);
    }
    const int lane = threadIdx.x & 63, wv = threadIdx.x >> 6;
    if (lane == 0) { s_acc[wv] = acc; s_cnt[wv] = cnt; }
    __syncthreads();
    if (threadIdx.x == 0)
        out[b] = (s_acc[0] + s_acc[1] + s_acc[2] + s_acc[3]) /
                 (s_cnt[0] + s_cnt[1] + s_cnt[2] + s_cnt[3]) + bias[0];
}

extern "C" void kernel_launch(void* const* d_in, const int* in_sizes, int n_in,
                              void* d_out, int out_size, void* d_ws, size_t ws_size,
                              hipStream_t stream) {
    const float* h    = (const float*)d_in[0];   // (B,T,C) fp32
    const float* W    = (const float*)d_in[1];   // (1,C)   fp32
    const float* bias = (const float*)d_in[2];   // (1,)    fp32
    const int*   ids  = (const int*)d_in[3];     // (B,T)   int32
    const int*   lens = (const int*)d_in[4];     // (B,)    int32

    float* out = (float*)d_out;                  // (B,) fp32
    float* p   = (float*)d_ws;                   // (B,T) fp32 scratch

    const size_t p_bytes    = (size_t)BB * TT * sizeof(float);   // 765,952
    const size_t done_bytes = BB * sizeof(int);                  // 512

    dim3 grid(BLOCKS_PER_ROW, BB);               // 374 x 128, 1 row per wave

    if (ws_size >= p_bytes + done_bytes) {
        int* done = (int*)((char*)d_ws + ws_size - done_bytes);  // tail of ws
        hipMemsetAsync(done, 0, done_bytes, stream);             // re-zero every call
        fused_kernel<<<grid, 256, 0, stream>>>(h, W, lens, bias, ids, p, done, out);
    } else {
        row_dot_kernel<<<grid, 256, 0, stream>>>(h, W, lens, p);
        finalize_kernel<<<BB, 256, 0, stream>>>(p, ids, lens, bias, out);
    }
}

// Round 6
// 82.734 us; speedup vs baseline: 25.7072x; 25.7072x over previous
//
#include <hip/hip_runtime.h>

#define BB 128
#define TT 1496
#define CC 768
#define NCHUNK 8
#define CH 187            // TT / NCHUNK exactly

// Kernel 1 (proven round-3 form): p[b,t] = dot(h[b,t,:], W) for t < len[b],
// 0 otherwise (every ws cell rewritten deterministically every call).
// One wave per (b,t) row; lane i reads float4 {i, i+64, i+128}.
__global__ __launch_bounds__(256) void row_dot_kernel(
    const float* __restrict__ h,      // (B,T,C)
    const float* __restrict__ W,      // (C)
    const int* __restrict__ lens,     // (B)
    float* __restrict__ p)            // (B,T) ws
{
    const int lane = threadIdx.x & 63;
    const int wv   = threadIdx.x >> 6;
    const int t    = blockIdx.x * 4 + wv;
    const int b    = blockIdx.y;
    if (t >= TT) return;
    if (t >= lens[b]) { if (lane == 0) p[b * TT + t] = 0.0f; return; }

    const float4* r  = reinterpret_cast<const float4*>(h + ((size_t)b * TT + t) * CC);
    const float4* w4 = reinterpret_cast<const float4*>(W);
    float4 a0 = r[lane], a1 = r[lane + 64], a2 = r[lane + 128];
    float4 w0 = w4[lane], w1 = w4[lane + 64], w2 = w4[lane + 128];
    float s = a0.x * w0.x + a0.y * w0.y + a0.z * w0.z + a0.w * w0.w
            + a1.x * w1.x + a1.y * w1.y + a1.z * w1.z + a1.w * w1.w
            + a2.x * w2.x + a2.y * w2.y + a2.z * w2.z + a2.w * w2.w;
    #pragma unroll
    for (int off = 32; off > 0; off >>= 1) s += __shfl_down(s, off, 64);
    if (lane == 0) p[b * TT + t] = s;
}

// Kernel 2: 8 chunk-blocks per batch row (1024 blocks total, ~16 waves/CU).
// Each block owns the runs STARTING in its 187-frame chunk (forward scan may
// cross the chunk boundary; runs avg ~1.01 frames). Writes its partial
// (sum of run means, run count) unconditionally -> deterministic, no zeroing.
__global__ __launch_bounds__(192) void finalize_partial_kernel(
    const float* __restrict__ p,      // (B,T) ws
    const int* __restrict__ ids,      // (B,T)
    const int* __restrict__ lens,     // (B)
    float2* __restrict__ partial)     // (B, NCHUNK) ws
{
    __shared__ float s_acc[3];
    __shared__ float s_cnt[3];

    const int chunk = blockIdx.x;     // 0..7
    const int b     = blockIdx.y;
    const int tid   = threadIdx.x;    // 0..191 (3 waves)

    int L = lens[b];
    if (L < 1) L = 1;
    if (L > TT) L = TT;

    const float* pr = p + b * TT;
    const int*   ir = ids + b * TT;

    const int cs = chunk * CH;
    const int ce = (cs + CH < L) ? cs + CH : L;

    float acc = 0.0f, cnt = 0.0f;
    const int t = cs + tid;
    if (t < ce) {
        int  id    = ir[t];
        bool start = (t == 0) || (ir[t - 1] != id);
        if (start) {
            float rs = pr[t];
            float rl = 1.0f;
            int   j  = t + 1;
            while (j < L && ir[j] == id) {   // may cross chunk boundary
                rs += pr[j];
                rl += 1.0f;
                ++j;
            }
            acc += rs / rl;
            cnt += 1.0f;
        }
    }

    #pragma unroll
    for (int off = 32; off > 0; off >>= 1) {
        acc += __shfl_down(acc, off, 64);
        cnt += __shfl_down(cnt, off, 64);
    }
    const int lane = tid & 63, wv = tid >> 6;
    if (lane == 0) { s_acc[wv] = acc; s_cnt[wv] = cnt; }
    __syncthreads();
    if (tid == 0) {
        float a = s_acc[0] + s_acc[1] + s_acc[2];
        float c = s_cnt[0] + s_cnt[1] + s_cnt[2];
        partial[b * NCHUNK + chunk] = make_float2(a, c);
    }
}

// Kernel 3: fold the 8 partials per row into the logit. 1 block, 128 threads.
__global__ __launch_bounds__(128) void reduce_final_kernel(
    const float2* __restrict__ partial,  // (B, NCHUNK)
    const float* __restrict__ bias,      // (1)
    float* __restrict__ out)             // (B)
{
    const int b = threadIdx.x;
    if (b >= BB) return;
    float a = 0.0f, c = 0.0f;
    #pragma unroll
    for (int k = 0; k < NCHUNK; ++k) {
        float2 v = partial[b * NCHUNK + k];
        a += v.x;
        c += v.y;
    }
    out[b] = a / c + bias[0];
}

// ---- fallback (proven round-3 single-block-per-row finalize) ----
__global__ __launch_bounds__(256) void finalize_kernel(
    const float* __restrict__ p, const int* __restrict__ ids,
    const int* __restrict__ lens, const float* __restrict__ bias,
    float* __restrict__ out)
{
    __shared__ float s_acc[4];
    __shared__ float s_cnt[4];
    const int b = blockIdx.x;
    int L = lens[b];
    if (L < 1) L = 1;
    if (L > TT) L = TT;
    const float* pr = p + b * TT;
    const int*   ir = ids + b * TT;
    float acc = 0.0f, cnt = 0.0f;
    for (int t = (int)threadIdx.x; t < L; t += 256) {
        int  id    = ir[t];
        bool start = (t == 0) || (ir[t - 1] != id);
        if (start) {
            float rs = pr[t]; float rl = 1.0f; int j = t + 1;
            while (j < L && ir[j] == id) { rs += pr[j]; rl += 1.0f; ++j; }
            acc += rs / rl; cnt += 1.0f;
        }
    }
    #pragma unroll
    for (int off = 32; off > 0; off >>= 1) {
        acc += __shfl_down(acc, off, 64);
        cnt += __shfl_down(cnt, off, 64);
    }
    const int lane = threadIdx.x & 63, wv = threadIdx.x >> 6;
    if (lane == 0) { s_acc[wv] = acc; s_cnt[wv] = cnt; }
    __syncthreads();
    if (threadIdx.x == 0)
        out[b] = (s_acc[0] + s_acc[1] + s_acc[2] + s_acc[3]) /
                 (s_cnt[0] + s_cnt[1] + s_cnt[2] + s_cnt[3]) + bias[0];
}

extern "C" void kernel_launch(void* const* d_in, const int* in_sizes, int n_in,
                              void* d_out, int out_size, void* d_ws, size_t ws_size,
                              hipStream_t stream) {
    const float* h    = (const float*)d_in[0];   // (B,T,C) fp32
    const float* W    = (const float*)d_in[1];   // (1,C)   fp32
    const float* bias = (const float*)d_in[2];   // (1,)    fp32
    const int*   ids  = (const int*)d_in[3];     // (B,T)   int32
    const int*   lens = (const int*)d_in[4];     // (B,)    int32

    float* out = (float*)d_out;                  // (B,) fp32
    float* p   = (float*)d_ws;                   // (B,T) fp32 scratch

    const size_t p_bytes       = (size_t)BB * TT * sizeof(float);      // 765,952
    const size_t partial_bytes = (size_t)BB * NCHUNK * sizeof(float2); // 8,192

    dim3 grid1((TT + 3) / 4, BB);                // 374 x 128
    row_dot_kernel<<<grid1, 256, 0, stream>>>(h, W, lens, p);

    if (ws_size >= p_bytes + partial_bytes) {
        float2* partial = (float2*)((char*)d_ws + p_bytes);
        dim3 grid2(NCHUNK, BB);                  // 1024 blocks, 192 thr each
        finalize_partial_kernel<<<grid2, 192, 0, stream>>>(p, ids, lens, partial);
        reduce_final_kernel<<<1, 128, 0, stream>>>(partial, bias, out);
    } else {
        finalize_kernel<<<BB, 256, 0, stream>>>(p, ids, lens, bias, out);
    }
}

// Round 8
// 73.359 us; speedup vs baseline: 28.9926x; 1.1278x over previous
//
#include <hip/hip_runtime.h>

#define BB 128
#define TT 1496
#define CC 768
#define NCHUNK 8
#define CH 187            // TT / NCHUNK exactly

typedef float vfloat4 __attribute__((ext_vector_type(4)));  // clang-native, nt-builtin compatible

// Kernel 1: p[b,t] = dot(h[b,t,:], W) for t < len[b], 0 otherwise (every ws
// cell rewritten deterministically every call). One wave per (b,t) row; lane
// i reads float4 {i, i+64, i+128}. h loads are NON-TEMPORAL: h is pure
// streaming (each byte read exactly once) - bypass cache allocation so the
// L2 keeps p/ids for the tail kernels and the stream avoids alloc overhead.
__global__ __launch_bounds__(256) void row_dot_kernel(
    const float* __restrict__ h,      // (B,T,C)
    const float* __restrict__ W,      // (C)
    const int* __restrict__ lens,     // (B)
    float* __restrict__ p)            // (B,T) ws
{
    const int lane = threadIdx.x & 63;
    const int wv   = threadIdx.x >> 6;
    const int t    = blockIdx.x * 4 + wv;
    const int b    = blockIdx.y;
    if (t >= TT) return;
    if (t >= lens[b]) { if (lane == 0) p[b * TT + t] = 0.0f; return; }

    const vfloat4* r  = reinterpret_cast<const vfloat4*>(h + ((size_t)b * TT + t) * CC);
    const vfloat4* w4 = reinterpret_cast<const vfloat4*>(W);
    vfloat4 a0 = __builtin_nontemporal_load(&r[lane]);
    vfloat4 a1 = __builtin_nontemporal_load(&r[lane + 64]);
    vfloat4 a2 = __builtin_nontemporal_load(&r[lane + 128]);
    vfloat4 w0 = w4[lane], w1 = w4[lane + 64], w2 = w4[lane + 128];

    vfloat4 acc4 = a0 * w0 + a1 * w1 + a2 * w2;
    float s = acc4.x + acc4.y + acc4.z + acc4.w;

    #pragma unroll
    for (int off = 32; off > 0; off >>= 1) s += __shfl_down(s, off, 64);
    if (lane == 0) p[b * TT + t] = s;
}

// Kernel 2: 8 chunk-blocks per batch row (1024 blocks, ~16 waves/CU). Each
// block owns the runs STARTING in its 187-frame chunk (forward scan may cross
// the chunk boundary; runs avg ~1.01 frames). Writes its partial
// (sum of run means, run count) unconditionally -> deterministic, no zeroing.
__global__ __launch_bounds__(192) void finalize_partial_kernel(
    const float* __restrict__ p,      // (B,T) ws
    const int* __restrict__ ids,      // (B,T)
    const int* __restrict__ lens,     // (B)
    float2* __restrict__ partial)     // (B, NCHUNK) ws
{
    __shared__ float s_acc[3];
    __shared__ float s_cnt[3];

    const int chunk = blockIdx.x;     // 0..7
    const int b     = blockIdx.y;
    const int tid   = threadIdx.x;    // 0..191 (3 waves)

    int L = lens[b];
    if (L < 1) L = 1;
    if (L > TT) L = TT;

    const float* pr = p + b * TT;
    const int*   ir = ids + b * TT;

    const int cs = chunk * CH;
    const int ce = (cs + CH < L) ? cs + CH : L;

    float acc = 0.0f, cnt = 0.0f;
    const int t = cs + tid;
    if (t < ce) {
        int  id    = ir[t];
        bool start = (t == 0) || (ir[t - 1] != id);
        if (start) {
            float rs = pr[t];
            float rl = 1.0f;
            int   j  = t + 1;
            while (j < L && ir[j] == id) {   // may cross chunk boundary
                rs += pr[j];
                rl += 1.0f;
                ++j;
            }
            acc += rs / rl;
            cnt += 1.0f;
        }
    }

    #pragma unroll
    for (int off = 32; off > 0; off >>= 1) {
        acc += __shfl_down(acc, off, 64);
        cnt += __shfl_down(cnt, off, 64);
    }
    const int lane = tid & 63, wv = tid >> 6;
    if (lane == 0) { s_acc[wv] = acc; s_cnt[wv] = cnt; }
    __syncthreads();
    if (tid == 0) {
        float a = s_acc[0] + s_acc[1] + s_acc[2];
        float c = s_cnt[0] + s_cnt[1] + s_cnt[2];
        partial[b * NCHUNK + chunk] = make_float2(a, c);
    }
}

// Kernel 3: fold the 8 partials per row into the logit. 1 block, 128 threads.
__global__ __launch_bounds__(128) void reduce_final_kernel(
    const float2* __restrict__ partial,  // (B, NCHUNK)
    const float* __restrict__ bias,      // (1)
    float* __restrict__ out)             // (B)
{
    const int b = threadIdx.x;
    if (b >= BB) return;
    float a = 0.0f, c = 0.0f;
    #pragma unroll
    for (int k = 0; k < NCHUNK; ++k) {
        float2 v = partial[b * NCHUNK + k];
        a += v.x;
        c += v.y;
    }
    out[b] = a / c + bias[0];
}

// ---- fallback (proven round-3 single-block-per-row finalize) ----
__global__ __launch_bounds__(256) void finalize_kernel(
    const float* __restrict__ p, const int* __restrict__ ids,
    const int* __restrict__ lens, const float* __restrict__ bias,
    float* __restrict__ out)
{
    __shared__ float s_acc[4];
    __shared__ float s_cnt[4];
    const int b = blockIdx.x;
    int L = lens[b];
    if (L < 1) L = 1;
    if (L > TT) L = TT;
    const float* pr = p + b * TT;
    const int*   ir = ids + b * TT;
    float acc = 0.0f, cnt = 0.0f;
    for (int t = (int)threadIdx.x; t < L; t += 256) {
        int  id    = ir[t];
        bool start = (t == 0) || (ir[t - 1] != id);
        if (start) {
            float rs = pr[t]; float rl = 1.0f; int j = t + 1;
            while (j < L && ir[j] == id) { rs += pr[j]; rl += 1.0f; ++j; }
            acc += rs / rl; cnt += 1.0f;
        }
    }
    #pragma unroll
    for (int off = 32; off > 0; off >>= 1) {
        acc += __shfl_down(acc, off, 64);
        cnt += __shfl_down(cnt, off, 64);
    }
    const int lane = threadIdx.x & 63, wv = threadIdx.x >> 6;
    if (lane == 0) { s_acc[wv] = acc; s_cnt[wv] = cnt; }
    __syncthreads();
    if (threadIdx.x == 0)
        out[b] = (s_acc[0] + s_acc[1] + s_acc[2] + s_acc[3]) /
                 (s_cnt[0] + s_cnt[1] + s_cnt[2] + s_cnt[3]) + bias[0];
}

extern "C" void kernel_launch(void* const* d_in, const int* in_sizes, int n_in,
                              void* d_out, int out_size, void* d_ws, size_t ws_size,
                              hipStream_t stream) {
    const float* h    = (const float*)d_in[0];   // (B,T,C) fp32
    const float* W    = (const float*)d_in[1];   // (1,C)   fp32
    const float* bias = (const float*)d_in[2];   // (1,)    fp32
    const int*   ids  = (const int*)d_in[3];     // (B,T)   int32
    const int*   lens = (const int*)d_in[4];     // (B,)    int32

    float* out = (float*)d_out;                  // (B,) fp32
    float* p   = (float*)d_ws;                   // (B,T) fp32 scratch

    const size_t p_bytes       = (size_t)BB * TT * sizeof(float);      // 765,952
    const size_t partial_bytes = (size_t)BB * NCHUNK * sizeof(float2); // 8,192

    dim3 grid1((TT + 3) / 4, BB);                // 374 x 128
    row_dot_kernel<<<grid1, 256, 0, stream>>>(h, W, lens, p);

    if (ws_size >= p_bytes + partial_bytes) {
        float2* partial = (float2*)((char*)d_ws + p_bytes);
        dim3 grid2(NCHUNK, BB);                  // 1024 blocks, 192 thr each
        finalize_partial_kernel<<<grid2, 192, 0, stream>>>(p, ids, lens, partial);
        reduce_final_kernel<<<1, 128, 0, stream>>>(partial, bias, out);
    } else {
        finalize_kernel<<<BB, 256, 0, stream>>>(p, ids, lens, bias, out);
    }
}